// Round 3
// baseline (1526.228 us; speedup 1.0000x reference)
//
#include <hip/hip_runtime.h>
#include <hip/hip_bf16.h>
#include <math.h>

#define DEVINL __device__ __forceinline__

typedef __bf16 bf16x8 __attribute__((ext_vector_type(8)));
typedef float  f32x4  __attribute__((ext_vector_type(4)));

DEVINL float bf2f(unsigned short h){ return __builtin_bit_cast(float, (unsigned)h << 16); }
DEVINL unsigned short f2bf(float f){
  unsigned u = __builtin_bit_cast(unsigned, f);
  u += 0x7fffu + ((u >> 16) & 1u);
  return (unsigned short)(u >> 16);
}

// ---- problem constants ----
#define Bn 32
#define Hn 56
#define Wn 56
#define Cn 192
#define WSz 7
#define SHIFTn 3
#define HEADSn 6
#define HDn 32
#define NWIN 49
#define NPIX (Bn*Hn*Wn)       /* 100352 == 2048*49 */
#define HIDDENn 768
#define KCONV (9*Cn)          /* 1728 */
#define PADH 58
#define QKSCALE 0.17677669529663687f

// chunking to bound d_ws footprint (~155 MB peak)
#define NCHUNK 8
#define WIN_PER_CHUNK 256                   /* 2048/8 */
#define ROWS_PER_CHUNK (WIN_PER_CHUNK*NWIN) /* 12544 */

DEVINL float wave_sum(float v){
  #pragma unroll
  for (int off=32; off; off>>=1) v += __shfl_xor(v, off, 64);
  return v;
}

// ---------------- LN1 (fp32 in) + roll(-3,-3) + window partition -> h [100352][192] bf16 ----------------
__global__ __launch_bounds__(256) void k_ln1(const float* __restrict__ x,
                                             const float* __restrict__ g,
                                             const float* __restrict__ bb,
                                             unsigned short* __restrict__ h)
{
  int row  = blockIdx.x*4 + (threadIdx.x >> 6);
  int lane = threadIdx.x & 63;
  int win = row / NWIN, n = row % NWIN;
  int b = win >> 6, rem = win & 63, wh = rem >> 3, ww = rem & 7;
  int i = n / WSz, j = n % WSz;
  int rr = (wh*WSz + i + SHIFTn) % Hn;
  int cc = (ww*WSz + j + SHIFTn) % Wn;
  const float* xr = x + (size_t)((b*Hn + rr)*Wn + cc)*Cn;
  float v0 = xr[lane], v1 = xr[lane+64], v2 = xr[lane+128];
  float s  = wave_sum(v0+v1+v2);
  float sq = wave_sum(v0*v0+v1*v1+v2*v2);
  float mu = s * (1.0f/Cn);
  float var = sq * (1.0f/Cn) - mu*mu;
  float rs = rsqrtf(var + 1e-3f);
  unsigned short* hr = h + (size_t)row*Cn;
  hr[lane]     = f2bf((v0-mu)*rs*g[lane]     + bb[lane]);
  hr[lane+64]  = f2bf((v1-mu)*rs*g[lane+64]  + bb[lane+64]);
  hr[lane+128] = f2bf((v2-mu)*rs*g[lane+128] + bb[lane+128]);
}

// ---------------- LN2 on xmid(fp32) -> zero-padded bf16 buffer [32][58][58][192] ----------------
__global__ __launch_bounds__(256) void k_ln2(const float* __restrict__ xmid,
                                             const float* __restrict__ g,
                                             const float* __restrict__ bb,
                                             unsigned short* __restrict__ out)
{
  int p    = blockIdx.x*4 + (threadIdx.x >> 6);
  int lane = threadIdx.x & 63;
  int b = p / (Hn*Wn), rc = p % (Hn*Wn);
  int r = rc / Wn, c = rc % Wn;
  const float* xr = xmid + (size_t)p*Cn;
  float v0 = xr[lane], v1 = xr[lane+64], v2 = xr[lane+128];
  float s  = wave_sum(v0+v1+v2);
  float sq = wave_sum(v0*v0+v1*v1+v2*v2);
  float mu = s * (1.0f/Cn);
  float var = sq * (1.0f/Cn) - mu*mu;
  float rs = rsqrtf(var + 1e-3f);
  unsigned short* orow = out + (size_t)((b*PADH + r + 1)*PADH + (c + 1))*Cn;
  orow[lane]     = f2bf((v0-mu)*rs*g[lane]     + bb[lane]);
  orow[lane+64]  = f2bf((v1-mu)*rs*g[lane+64]  + bb[lane+64]);
  orow[lane+128] = f2bf((v2-mu)*rs*g[lane+128] + bb[lane+128]);
}

// ---------------- transpose + fp32->bf16: out[n*K+k] = bf16(in[k*N+n]) ----------------
__global__ __launch_bounds__(256) void k_transpose(const float* __restrict__ in,
                                                   unsigned short* __restrict__ out,
                                                   int K, int N)
{
  int idx = blockIdx.x*256 + threadIdx.x;
  if (idx < K*N){ int k = idx / N, n = idx - k*N; out[(size_t)n*K + k] = f2bf(in[idx]); }
}

// ---------------- fused windowed attention: one block per (head, chunk-local window) ----------------
__global__ __launch_bounds__(256) void k_attn(const unsigned short* __restrict__ qkv, // chunk-local bf16
                                              const float* __restrict__ bias_table,   // fp32
                                              unsigned short* __restrict__ o,          // global rows bf16
                                              int win_base)
{
  __shared__ float qs[NWIN][HDn], ks[NWIN][HDn], vs[NWIN][HDn], S[NWIN][NWIN+1];
  int head = blockIdx.x, lwin = blockIdx.y;
  int gwin = win_base + lwin;
  int tid = threadIdx.x;
  const unsigned short* base = qkv + (size_t)lwin*NWIN*576 + head*HDn;
  for (int t = tid; t < NWIN*HDn; t += 256){
    int n = t >> 5, d = t & 31;
    const unsigned short* rp = base + (size_t)n*576 + d;
    qs[n][d] = bf2f(rp[0]) * QKSCALE;
    ks[n][d] = bf2f(rp[192]);
    vs[n][d] = bf2f(rp[384]);
  }
  __syncthreads();
  int rem = gwin & 63, wh = rem >> 3, ww = rem & 7;
  for (int t = tid; t < NWIN*NWIN; t += 256){
    int p = t / NWIN, q = t - p*NWIN;
    float acc = 0.f;
    #pragma unroll
    for (int d = 0; d < HDn; ++d) acc += qs[p][d]*ks[q][d];
    int pi = p/7, pj = p%7, qi = q/7, qj = q%7;
    int rel = (pi-qi+6)*13 + (pj-qj+6);
    acc += bias_table[rel*HEADSn + head];
    int pr = wh*7+pi, pc = ww*7+pj, qr = wh*7+qi, qc = ww*7+qj;
    int cp = (pr<49?0:(pr<53?1:2))*3 + (pc<49?0:(pc<53?1:2));
    int cq = (qr<49?0:(qr<53?1:2))*3 + (qc<49?0:(qc<53?1:2));
    if (cp != cq) acc -= 100.0f;
    S[p][q] = acc;
  }
  __syncthreads();
  if (tid < NWIN){
    float m = -1e30f;
    for (int q=0;q<NWIN;++q) m = fmaxf(m, S[tid][q]);
    float sum = 0.f;
    for (int q=0;q<NWIN;++q){ float e = expf(S[tid][q]-m); S[tid][q]=e; sum+=e; }
    float inv = 1.0f/sum;
    for (int q=0;q<NWIN;++q) S[tid][q] *= inv;
  }
  __syncthreads();
  for (int t = tid; t < NWIN*HDn; t += 256){
    int n = t >> 5, d = t & 31;
    float acc = 0.f;
    for (int m=0;m<NWIN;++m) acc += S[n][m]*vs[m][d];
    o[((size_t)gwin*NWIN + n)*Cn + head*HDn + d] = f2bf(acc);
  }
}

// ---------------- MFMA GEMM: C = A(bf16) * Bt(bf16)^T, 4 epilogues ----------------
// AMODE 0: A direct [.][K] at rows (a_rbase + local).  AMODE 1: implicit im2col from
//          padded ln2 [32][58][58][192], pixel = a_rbase + local.
// EPI 0: +bias(e0 fp32) -> bf16 out[lrow*576+col]
// EPI 1: +bias(e0), window-reverse+roll scatter, +shortcut(e2 fp32) -> fp32 out (global rows)
// EPI 2: *e0+e1 (fp32), exact GELU -> bf16 out[lrow*768+col]
// EPI 3: *e0+e1 (fp32), + e2(fp32 xmid, global rows) -> fp32 out (global rows)
#define BM 64
#define BN 64
#define BK 32
#define BKP 40

template<int AMODE, int EPI>
__global__ __launch_bounds__(256) void k_gemm(const unsigned short* __restrict__ A,
                                              const unsigned short* __restrict__ Bt,
                                              int K, int a_rbase, int o_rbase,
                                              const float* __restrict__ e0,
                                              const float* __restrict__ e1,
                                              const float* __restrict__ e2,
                                              void* __restrict__ out)
{
  __shared__ __align__(16) unsigned short As[BM*BKP];
  __shared__ __align__(16) unsigned short Bs[BN*BKP];
  int tid = threadIdx.x;
  int bm = blockIdx.y * BM, bn = blockIdx.x * BN;
  int wave = tid >> 6, lane = tid & 63;
  int l15 = lane & 15, quad = lane >> 4;
  int wm = (wave & 1) * 32, wn = (wave >> 1) * 32;

  int ar = tid >> 2;           // tile row this thread stages
  int kc = (tid & 3) * 8;      // k offset within BK

  int lrow = bm + ar;          // chunk-local row
  size_t a_base;
  if (AMODE == 0) a_base = (size_t)(a_rbase + lrow) * K + kc;
  else {
    int grow = a_rbase + lrow;
    int b = grow / (Hn*Wn), rc = grow % (Hn*Wn);
    int r = rc / Wn, c = rc - r*Wn;
    a_base = (size_t)((b*PADH + r)*PADH + c) * Cn;
  }
  size_t b_base = (size_t)(bn + ar) * K + kc;

  f32x4 acc[2][2] = {};

  int nkb = K / BK;
  for (int kb = 0; kb < nkb; ++kb){
    int k0 = kb * BK;
    uint4 av, bv;
    if (AMODE == 0) av = *(const uint4*)(A + a_base + k0);
    else {
      int kk = k0 + kc;
      int tap = kk / Cn;            // uniform over the BK block (192 % 32 == 0)
      int ci  = kk - tap*Cn;
      int dh = tap/3, dw = tap - dh*3;
      av = *(const uint4*)(A + a_base + (size_t)((dh*PADH + dw)*Cn + ci));
    }
    bv = *(const uint4*)(Bt + b_base + k0);
    __syncthreads();
    *(uint4*)&As[ar*BKP + kc] = av;
    *(uint4*)&Bs[ar*BKP + kc] = bv;
    __syncthreads();

    bf16x8 af0 = *(const bf16x8*)&As[(wm      + l15)*BKP + quad*8];
    bf16x8 af1 = *(const bf16x8*)&As[(wm + 16 + l15)*BKP + quad*8];
    bf16x8 bf0 = *(const bf16x8*)&Bs[(wn      + l15)*BKP + quad*8];
    bf16x8 bf1 = *(const bf16x8*)&Bs[(wn + 16 + l15)*BKP + quad*8];
    acc[0][0] = __builtin_amdgcn_mfma_f32_16x16x32_bf16(af0, bf0, acc[0][0], 0,0,0);
    acc[0][1] = __builtin_amdgcn_mfma_f32_16x16x32_bf16(af0, bf1, acc[0][1], 0,0,0);
    acc[1][0] = __builtin_amdgcn_mfma_f32_16x16x32_bf16(af1, bf0, acc[1][0], 0,0,0);
    acc[1][1] = __builtin_amdgcn_mfma_f32_16x16x32_bf16(af1, bf1, acc[1][1], 0,0,0);
  }

  #pragma unroll
  for (int mt=0; mt<2; ++mt)
  #pragma unroll
  for (int nt=0; nt<2; ++nt){
    f32x4 a4 = acc[mt][nt];
    int gcol = bn + wn + nt*16 + l15;
    #pragma unroll
    for (int r=0; r<4; ++r){
      int orow = bm + wm + mt*16 + quad*4 + r;   // chunk-local
      float v = a4[r];
      if (EPI == 0){
        v += e0[gcol];
        ((unsigned short*)out)[(size_t)orow*576 + gcol] = f2bf(v);
      } else if (EPI == 1){
        v += e0[gcol];
        int grow = o_rbase + orow;
        int win = grow / NWIN, n = grow - win*NWIN;
        int b = win >> 6, rem2 = win & 63, wh = rem2 >> 3, ww = rem2 & 7;
        int ii = n / WSz, jj = n - ii*WSz;
        int fr = (wh*WSz + ii + SHIFTn) % Hn;
        int fc = (ww*WSz + jj + SHIFTn) % Wn;
        size_t idx = (size_t)((b*Hn + fr)*Wn + fc)*Cn + gcol;
        ((float*)out)[idx] = e2[idx] + v;
      } else if (EPI == 2){
        v = v * e0[gcol] + e1[gcol];
        v = 0.5f * v * (1.0f + erff(v * 0.7071067811865476f));
        ((unsigned short*)out)[(size_t)orow*HIDDENn + gcol] = f2bf(v);
      } else {
        v = v * e0[gcol] + e1[gcol];
        int grow = o_rbase + orow;
        v += e2[(size_t)grow*Cn + gcol];
        ((float*)out)[(size_t)grow*Cn + gcol] = v;
      }
    }
  }
}

// ---------------- workspace layout (bytes) — peak ~155.4 MB ----------------
#define OFF_A      ((size_t)0)           // h (38,535,168) then ln2pad (41,336,832)
#define OFF_QC     ((size_t)41337344)    // qkv chunk: 12544*576*2   = 14,450,688
#define OFF_XMID   ((size_t)55788032)    // fp32 NPIX*192*4          = 77,070,336
#define OFF_HC     ((size_t)132858368)   // hidden chunk: 12544*768*2= 19,267,584
#define OFF_WTQ    ((size_t)152125952)   // 221,184
#define OFF_WTP    ((size_t)152347136)   // 73,728
#define OFF_WTF1   ((size_t)152420864)   // 2,654,208
#define OFF_WTF2   ((size_t)155075072)   // 294,912 -> end 155,369,984

extern "C" void kernel_launch(void* const* d_in, const int* in_sizes, int n_in,
                              void* d_out, int out_size, void* d_ws, size_t ws_size,
                              hipStream_t stream)
{
  const float* x        = (const float*)d_in[0];
  const float* ln1_g    = (const float*)d_in[1];
  const float* ln1_b    = (const float*)d_in[2];
  const float* w_qkv    = (const float*)d_in[3];
  const float* b_qkv    = (const float*)d_in[4];
  const float* btab     = (const float*)d_in[5];
  const float* w_proj   = (const float*)d_in[6];
  const float* b_proj   = (const float*)d_in[7];
  const float* ln2_g    = (const float*)d_in[8];
  const float* ln2_b    = (const float*)d_in[9];
  const float* w_ffn1   = (const float*)d_in[10];
  const float* bn1_s    = (const float*)d_in[11];
  const float* bn1_sh   = (const float*)d_in[12];
  const float* w_ffn2   = (const float*)d_in[13];
  const float* bn2_s    = (const float*)d_in[14];
  const float* bn2_sh   = (const float*)d_in[15];

  char* ws = (char*)d_ws;
  unsigned short* h      = (unsigned short*)(ws + OFF_A);
  unsigned short* ln2pad = (unsigned short*)(ws + OFF_A);
  unsigned short* qc     = (unsigned short*)(ws + OFF_QC);
  float*          xmid   = (float*)(ws + OFF_XMID);
  unsigned short* hc     = (unsigned short*)(ws + OFF_HC);
  unsigned short* wTq    = (unsigned short*)(ws + OFF_WTQ);
  unsigned short* wTp    = (unsigned short*)(ws + OFF_WTP);
  unsigned short* wTf1   = (unsigned short*)(ws + OFF_WTF1);
  unsigned short* wTf2   = (unsigned short*)(ws + OFF_WTF2);
  float*          outp   = (float*)d_out;
  unsigned short* obuf   = (unsigned short*)d_out;   // bf16 scratch: dead before final fp32 write

  dim3 blk(256);

  // weight transposes + bf16 cast (tiny)
  k_transpose<<<(192*576 + 255)/256,  blk, 0, stream>>>(w_qkv,  wTq,  192, 576);
  k_transpose<<<(192*192 + 255)/256,  blk, 0, stream>>>(w_proj, wTp,  192, 192);
  k_transpose<<<(1728*768 + 255)/256, blk, 0, stream>>>(w_ffn1, wTf1, 1728, 768);
  k_transpose<<<(768*192 + 255)/256,  blk, 0, stream>>>(w_ffn2, wTf2, 768, 192);

  // LN1 + roll + window partition (fp32 -> bf16)
  k_ln1<<<NPIX/4, blk, 0, stream>>>(x, ln1_g, ln1_b, h);

  // QKV GEMM + attention, 8 chunks of 256 windows
  for (int c = 0; c < NCHUNK; ++c){
    int rbase = c * ROWS_PER_CHUNK;
    k_gemm<0,0><<<dim3(576/BN, ROWS_PER_CHUNK/BM), blk, 0, stream>>>(
        h, wTq, 192, rbase, 0, b_qkv, nullptr, nullptr, qc);
    k_attn<<<dim3(HEADSn, WIN_PER_CHUNK), blk, 0, stream>>>(qc, btab, obuf, c*WIN_PER_CHUNK);
  }

  // proj GEMM + window reverse + roll + shortcut(x fp32) -> xmid (fp32), full M
  k_gemm<0,1><<<dim3(192/BN, NPIX/BM), blk, 0, stream>>>(
      obuf, wTp, 192, 0, 0, b_proj, nullptr, x, xmid);

  // LN2 into zero-padded bf16 buffer
  hipMemsetAsync(ln2pad, 0, (size_t)Bn*PADH*PADH*Cn*2, stream);
  k_ln2<<<NPIX/4, blk, 0, stream>>>(xmid, ln2_g, ln2_b, ln2pad);

  // FFN: conv3x3(im2col)+bn1+GELU -> hc; conv1x1+bn2+residual -> fp32 out, 8 row-chunks
  for (int c = 0; c < NCHUNK; ++c){
    int rbase = c * ROWS_PER_CHUNK;
    k_gemm<1,2><<<dim3(HIDDENn/BN, ROWS_PER_CHUNK/BM), blk, 0, stream>>>(
        ln2pad, wTf1, KCONV, rbase, 0, bn1_s, bn1_sh, nullptr, hc);
    k_gemm<0,3><<<dim3(192/BN, ROWS_PER_CHUNK/BM), blk, 0, stream>>>(
        hc, wTf2, 768, 0, rbase, bn2_s, bn2_sh, xmid, outp);
  }
}

// Round 4
// 1412.862 us; speedup vs baseline: 1.0802x; 1.0802x over previous
//
#include <hip/hip_runtime.h>
#include <hip/hip_bf16.h>
#include <math.h>

#define DEVINL __device__ __forceinline__

typedef __bf16 bf16x8 __attribute__((ext_vector_type(8)));
typedef float  f32x4  __attribute__((ext_vector_type(4)));

DEVINL float bf2f(unsigned short h){ return __builtin_bit_cast(float, (unsigned)h << 16); }
DEVINL unsigned short f2bf(float f){
  unsigned u = __builtin_bit_cast(unsigned, f);
  u += 0x7fffu + ((u >> 16) & 1u);
  return (unsigned short)(u >> 16);
}

// direct global->LDS DMA, 16B per lane (lds dest must be wave-uniform base + lane*16)
DEVINL void gl16(const unsigned short* g, unsigned short* l){
  __builtin_amdgcn_global_load_lds((const __attribute__((address_space(1))) unsigned int*)g,
                                   (__attribute__((address_space(3))) unsigned int*)l,
                                   16, 0, 0);
}

// ---- problem constants ----
#define Bn 32
#define Hn 56
#define Wn 56
#define Cn 192
#define WSz 7
#define SHIFTn 3
#define HEADSn 6
#define HDn 32
#define NWIN 49
#define NPIX (Bn*Hn*Wn)       /* 100352 == 2048*49 */
#define HIDDENn 768
#define KCONV (9*Cn)          /* 1728 */
#define PADH 58
#define QKSCALE 0.17677669529663687f

// chunking to bound d_ws footprint (~155 MB peak)
#define NCHUNK 8
#define WIN_PER_CHUNK 256                   /* 2048/8 */
#define ROWS_PER_CHUNK (WIN_PER_CHUNK*NWIN) /* 12544 */

DEVINL float wave_sum(float v){
  #pragma unroll
  for (int off=32; off; off>>=1) v += __shfl_xor(v, off, 64);
  return v;
}

// ---------------- LN1 (fp32 in) + roll(-3,-3) + window partition -> h [100352][192] bf16 ----------------
__global__ __launch_bounds__(256) void k_ln1(const float* __restrict__ x,
                                             const float* __restrict__ g,
                                             const float* __restrict__ bb,
                                             unsigned short* __restrict__ h)
{
  int row  = blockIdx.x*4 + (threadIdx.x >> 6);
  int lane = threadIdx.x & 63;
  int win = row / NWIN, n = row % NWIN;
  int b = win >> 6, rem = win & 63, wh = rem >> 3, ww = rem & 7;
  int i = n / WSz, j = n % WSz;
  int rr = (wh*WSz + i + SHIFTn) % Hn;
  int cc = (ww*WSz + j + SHIFTn) % Wn;
  const float* xr = x + (size_t)((b*Hn + rr)*Wn + cc)*Cn;
  float v0 = xr[lane], v1 = xr[lane+64], v2 = xr[lane+128];
  float s  = wave_sum(v0+v1+v2);
  float sq = wave_sum(v0*v0+v1*v1+v2*v2);
  float mu = s * (1.0f/Cn);
  float var = sq * (1.0f/Cn) - mu*mu;
  float rs = rsqrtf(var + 1e-3f);
  unsigned short* hr = h + (size_t)row*Cn;
  hr[lane]     = f2bf((v0-mu)*rs*g[lane]     + bb[lane]);
  hr[lane+64]  = f2bf((v1-mu)*rs*g[lane+64]  + bb[lane+64]);
  hr[lane+128] = f2bf((v2-mu)*rs*g[lane+128] + bb[lane+128]);
}

// ---------------- LN2 on xmid(fp32) -> zero-padded bf16 buffer [32][58][58][192] ----------------
__global__ __launch_bounds__(256) void k_ln2(const float* __restrict__ xmid,
                                             const float* __restrict__ g,
                                             const float* __restrict__ bb,
                                             unsigned short* __restrict__ out)
{
  int p    = blockIdx.x*4 + (threadIdx.x >> 6);
  int lane = threadIdx.x & 63;
  int b = p / (Hn*Wn), rc = p % (Hn*Wn);
  int r = rc / Wn, c = rc % Wn;
  const float* xr = xmid + (size_t)p*Cn;
  float v0 = xr[lane], v1 = xr[lane+64], v2 = xr[lane+128];
  float s  = wave_sum(v0+v1+v2);
  float sq = wave_sum(v0*v0+v1*v1+v2*v2);
  float mu = s * (1.0f/Cn);
  float var = sq * (1.0f/Cn) - mu*mu;
  float rs = rsqrtf(var + 1e-3f);
  unsigned short* orow = out + (size_t)((b*PADH + r + 1)*PADH + (c + 1))*Cn;
  orow[lane]     = f2bf((v0-mu)*rs*g[lane]     + bb[lane]);
  orow[lane+64]  = f2bf((v1-mu)*rs*g[lane+64]  + bb[lane+64]);
  orow[lane+128] = f2bf((v2-mu)*rs*g[lane+128] + bb[lane+128]);
}

// ---------------- transpose + fp32->bf16: out[n*K+k] = bf16(in[k*N+n]) ----------------
__global__ __launch_bounds__(256) void k_transpose(const float* __restrict__ in,
                                                   unsigned short* __restrict__ out,
                                                   int K, int N)
{
  int idx = blockIdx.x*256 + threadIdx.x;
  if (idx < K*N){ int k = idx / N, n = idx - k*N; out[(size_t)n*K + k] = f2bf(in[idx]); }
}

// ---------------- fused windowed attention: one block per (head, chunk-local window) ----------------
__global__ __launch_bounds__(256) void k_attn(const unsigned short* __restrict__ qkv, // chunk-local bf16
                                              const float* __restrict__ bias_table,   // fp32
                                              unsigned short* __restrict__ o,          // global rows bf16
                                              int win_base)
{
  __shared__ float qs[NWIN][HDn], ks[NWIN][HDn], vs[NWIN][HDn], S[NWIN][NWIN+1];
  int head = blockIdx.x, lwin = blockIdx.y;
  int gwin = win_base + lwin;
  int tid = threadIdx.x;
  const unsigned short* base = qkv + (size_t)lwin*NWIN*576 + head*HDn;
  for (int t = tid; t < NWIN*HDn; t += 256){
    int n = t >> 5, d = t & 31;
    const unsigned short* rp = base + (size_t)n*576 + d;
    qs[n][d] = bf2f(rp[0]) * QKSCALE;
    ks[n][d] = bf2f(rp[192]);
    vs[n][d] = bf2f(rp[384]);
  }
  __syncthreads();
  int rem = gwin & 63, wh = rem >> 3, ww = rem & 7;
  for (int t = tid; t < NWIN*NWIN; t += 256){
    int p = t / NWIN, q = t - p*NWIN;
    float acc = 0.f;
    #pragma unroll
    for (int d = 0; d < HDn; ++d) acc += qs[p][d]*ks[q][d];
    int pi = p/7, pj = p%7, qi = q/7, qj = q%7;
    int rel = (pi-qi+6)*13 + (pj-qj+6);
    acc += bias_table[rel*HEADSn + head];
    int pr = wh*7+pi, pc = ww*7+pj, qr = wh*7+qi, qc = ww*7+qj;
    int cp = (pr<49?0:(pr<53?1:2))*3 + (pc<49?0:(pc<53?1:2));
    int cq = (qr<49?0:(qr<53?1:2))*3 + (qc<49?0:(qc<53?1:2));
    if (cp != cq) acc -= 100.0f;
    S[p][q] = acc;
  }
  __syncthreads();
  if (tid < NWIN){
    float m = -1e30f;
    for (int q=0;q<NWIN;++q) m = fmaxf(m, S[tid][q]);
    float sum = 0.f;
    for (int q=0;q<NWIN;++q){ float e = expf(S[tid][q]-m); S[tid][q]=e; sum+=e; }
    float inv = 1.0f/sum;
    for (int q=0;q<NWIN;++q) S[tid][q] *= inv;
  }
  __syncthreads();
  for (int t = tid; t < NWIN*HDn; t += 256){
    int n = t >> 5, d = t & 31;
    float acc = 0.f;
    for (int m=0;m<NWIN;++m) acc += S[n][m]*vs[m][d];
    o[((size_t)gwin*NWIN + n)*Cn + head*HDn + d] = f2bf(acc);
  }
}

// ---------------- MFMA GEMM (m97 structure): C = A(bf16) * Bt(bf16)^T ----------------
// Tile BMt x BNt (BMt,BNt in {64,128}), BK=32, 4 waves in 2x2, each wave
// computes (BMt/2)x(BNt/2) via (BMt/32)x(BNt/32) frags of 16x16x32 MFMA.
// Staging: direct global->LDS DMA, unpadded As[BMt][32]/Bs[BNt][32]
// (lane-ordered: LDS byte offset == tid*16 per 64-row issue).
// AMODE 0: A direct [.][K] at rows (a_rbase + local).  AMODE 1: implicit im2col from
//          padded ln2 [32][58][58][192], pixel = a_rbase + local (tap uniform per BK: 192%32==0).
// EPI 0: +bias(e0) -> bf16 out[lrow*576+col]
// EPI 1: +bias(e0), window-reverse+roll scatter, +shortcut(e2 fp32) -> fp32 out (global rows)
// EPI 2: *e0+e1, exact GELU -> bf16 out[lrow*768+col]
// EPI 3: *e0+e1, + e2(fp32 xmid, global rows) -> fp32 out (global rows)
template<int AMODE, int EPI, int BMt, int BNt>
__global__ __launch_bounds__(256) void k_gemm(const unsigned short* __restrict__ A,
                                              const unsigned short* __restrict__ Bt,
                                              int K, int a_rbase, int o_rbase,
                                              const float* __restrict__ e0,
                                              const float* __restrict__ e1,
                                              const float* __restrict__ e2,
                                              void* __restrict__ out)
{
  constexpr int WMT = BMt/32, WNT = BNt/32;   // frags per wave
  constexpr int NIA = BMt/64, NIB = BNt/64;   // 64-row staging issues
  __shared__ __align__(16) unsigned short As[BMt*32];
  __shared__ __align__(16) unsigned short Bs[BNt*32];
  int tid = threadIdx.x;
  int bm = blockIdx.y * BMt, bn = blockIdx.x * BNt;
  int wave = tid >> 6, lane = tid & 63;
  int l15 = lane & 15, quad = lane >> 4;
  int wm = (wave & 1) * (BMt/2), wn = (wave >> 1) * (BNt/2);

  int srow = tid >> 2;          // staging row within a 64-row issue
  int kc   = (tid & 3) * 8;     // k element offset (8 bf16 = 16 B)

  size_t abase[NIA];
  #pragma unroll
  for (int i=0;i<NIA;++i){
    int lrow = bm + i*64 + srow;
    if (AMODE == 0) abase[i] = (size_t)(a_rbase + lrow) * K + kc;
    else {
      int grow = a_rbase + lrow;
      int b = grow / (Hn*Wn), rc = grow % (Hn*Wn);
      int r = rc / Wn, c = rc - r*Wn;
      abase[i] = (size_t)((b*PADH + r)*PADH + c) * Cn + kc;
    }
  }
  size_t bbase[NIB];
  #pragma unroll
  for (int i=0;i<NIB;++i) bbase[i] = (size_t)(bn + i*64 + srow) * K + kc;

  f32x4 acc[WMT][WNT] = {};

  int nkb = K / 32;
  for (int kb = 0; kb < nkb; ++kb){
    int k0 = kb * 32;
    size_t aoff;
    if (AMODE == 0) aoff = (size_t)k0;
    else {
      int tap = k0 / Cn, ci = k0 - tap*Cn;   // uniform across BK block
      int dh = tap/3, dw = tap - dh*3;
      aoff = (size_t)((dh*PADH + dw)*Cn + ci);
    }
    #pragma unroll
    for (int i=0;i<NIA;++i)
      gl16(A + abase[i] + aoff, &As[i*64*32] + (size_t)tid*8);
    #pragma unroll
    for (int i=0;i<NIB;++i)
      gl16(Bt + bbase[i] + (size_t)k0, &Bs[i*64*32] + (size_t)tid*8);
    __syncthreads();   // drains vmcnt: DMA complete

    bf16x8 af[WMT], bfr[WNT];
    #pragma unroll
    for (int mt=0;mt<WMT;++mt) af[mt]  = *(const bf16x8*)&As[(wm + mt*16 + l15)*32 + quad*8];
    #pragma unroll
    for (int nt=0;nt<WNT;++nt) bfr[nt] = *(const bf16x8*)&Bs[(wn + nt*16 + l15)*32 + quad*8];
    #pragma unroll
    for (int mt=0;mt<WMT;++mt)
      #pragma unroll
      for (int nt=0;nt<WNT;++nt)
        acc[mt][nt] = __builtin_amdgcn_mfma_f32_16x16x32_bf16(af[mt], bfr[nt], acc[mt][nt], 0,0,0);
    __syncthreads();   // all consumers done before next overwrite
  }

  #pragma unroll
  for (int mt=0; mt<WMT; ++mt)
  #pragma unroll
  for (int nt=0; nt<WNT; ++nt){
    f32x4 a4 = acc[mt][nt];
    int gcol = bn + wn + nt*16 + l15;
    #pragma unroll
    for (int r=0; r<4; ++r){
      int orow = bm + wm + mt*16 + quad*4 + r;   // chunk-local
      float v = a4[r];
      if (EPI == 0){
        v += e0[gcol];
        ((unsigned short*)out)[(size_t)orow*576 + gcol] = f2bf(v);
      } else if (EPI == 1){
        v += e0[gcol];
        int grow = o_rbase + orow;
        int win = grow / NWIN, n = grow - win*NWIN;
        int b = win >> 6, rem2 = win & 63, wh = rem2 >> 3, ww = rem2 & 7;
        int ii = n / WSz, jj = n - ii*WSz;
        int fr = (wh*WSz + ii + SHIFTn) % Hn;
        int fc = (ww*WSz + jj + SHIFTn) % Wn;
        size_t idx = (size_t)((b*Hn + fr)*Wn + fc)*Cn + gcol;
        ((float*)out)[idx] = e2[idx] + v;
      } else if (EPI == 2){
        v = v * e0[gcol] + e1[gcol];
        v = 0.5f * v * (1.0f + erff(v * 0.7071067811865476f));
        ((unsigned short*)out)[(size_t)orow*HIDDENn + gcol] = f2bf(v);
      } else {
        v = v * e0[gcol] + e1[gcol];
        int grow = o_rbase + orow;
        v += e2[(size_t)grow*Cn + gcol];
        ((float*)out)[(size_t)grow*Cn + gcol] = v;
      }
    }
  }
}

// ---------------- workspace layout (bytes) — peak ~155.4 MB ----------------
#define OFF_A      ((size_t)0)           // h (38,535,168) then ln2pad (41,336,832)
#define OFF_QC     ((size_t)41337344)    // qkv chunk: 12544*576*2   = 14,450,688
#define OFF_XMID   ((size_t)55788032)    // fp32 NPIX*192*4          = 77,070,336
#define OFF_HC     ((size_t)132858368)   // hidden chunk: 12544*768*2= 19,267,584
#define OFF_WTQ    ((size_t)152125952)   // 221,184
#define OFF_WTP    ((size_t)152347136)   // 73,728
#define OFF_WTF1   ((size_t)152420864)   // 2,654,208
#define OFF_WTF2   ((size_t)155075072)   // 294,912 -> end 155,369,984

extern "C" void kernel_launch(void* const* d_in, const int* in_sizes, int n_in,
                              void* d_out, int out_size, void* d_ws, size_t ws_size,
                              hipStream_t stream)
{
  const float* x        = (const float*)d_in[0];
  const float* ln1_g    = (const float*)d_in[1];
  const float* ln1_b    = (const float*)d_in[2];
  const float* w_qkv    = (const float*)d_in[3];
  const float* b_qkv    = (const float*)d_in[4];
  const float* btab     = (const float*)d_in[5];
  const float* w_proj   = (const float*)d_in[6];
  const float* b_proj   = (const float*)d_in[7];
  const float* ln2_g    = (const float*)d_in[8];
  const float* ln2_b    = (const float*)d_in[9];
  const float* w_ffn1   = (const float*)d_in[10];
  const float* bn1_s    = (const float*)d_in[11];
  const float* bn1_sh   = (const float*)d_in[12];
  const float* w_ffn2   = (const float*)d_in[13];
  const float* bn2_s    = (const float*)d_in[14];
  const float* bn2_sh   = (const float*)d_in[15];

  char* ws = (char*)d_ws;
  unsigned short* h      = (unsigned short*)(ws + OFF_A);
  unsigned short* ln2pad = (unsigned short*)(ws + OFF_A);
  unsigned short* qc     = (unsigned short*)(ws + OFF_QC);
  float*          xmid   = (float*)(ws + OFF_XMID);
  unsigned short* hc     = (unsigned short*)(ws + OFF_HC);
  unsigned short* wTq    = (unsigned short*)(ws + OFF_WTQ);
  unsigned short* wTp    = (unsigned short*)(ws + OFF_WTP);
  unsigned short* wTf1   = (unsigned short*)(ws + OFF_WTF1);
  unsigned short* wTf2   = (unsigned short*)(ws + OFF_WTF2);
  float*          outp   = (float*)d_out;
  unsigned short* obuf   = (unsigned short*)d_out;   // bf16 scratch: dead before final fp32 write

  dim3 blk(256);

  // weight transposes + bf16 cast (tiny)
  k_transpose<<<(192*576 + 255)/256,  blk, 0, stream>>>(w_qkv,  wTq,  192, 576);
  k_transpose<<<(192*192 + 255)/256,  blk, 0, stream>>>(w_proj, wTp,  192, 192);
  k_transpose<<<(1728*768 + 255)/256, blk, 0, stream>>>(w_ffn1, wTf1, 1728, 768);
  k_transpose<<<(768*192 + 255)/256,  blk, 0, stream>>>(w_ffn2, wTf2, 768, 192);

  // LN1 + roll + window partition (fp32 -> bf16)
  k_ln1<<<NPIX/4, blk, 0, stream>>>(x, ln1_g, ln1_b, h);

  // QKV GEMM + attention, 8 chunks of 256 windows
  for (int c = 0; c < NCHUNK; ++c){
    int rbase = c * ROWS_PER_CHUNK;
    k_gemm<0,0,128,64><<<dim3(576/64, ROWS_PER_CHUNK/128), blk, 0, stream>>>(
        h, wTq, 192, rbase, 0, b_qkv, nullptr, nullptr, qc);
    k_attn<<<dim3(HEADSn, WIN_PER_CHUNK), blk, 0, stream>>>(qc, btab, obuf, c*WIN_PER_CHUNK);
  }

  // proj GEMM + window reverse + roll + shortcut(x fp32) -> xmid (fp32), full M
  k_gemm<0,1,128,64><<<dim3(192/64, NPIX/128), blk, 0, stream>>>(
      obuf, wTp, 192, 0, 0, b_proj, nullptr, x, xmid);

  // LN2 into zero-padded bf16 buffer
  hipMemsetAsync(ln2pad, 0, (size_t)Bn*PADH*PADH*Cn*2, stream);
  k_ln2<<<NPIX/4, blk, 0, stream>>>(xmid, ln2_g, ln2_b, ln2pad);

  // FFN: conv3x3(im2col)+bn1+GELU -> hc; conv1x1+bn2+residual -> fp32 out, 8 row-chunks
  for (int c = 0; c < NCHUNK; ++c){
    int rbase = c * ROWS_PER_CHUNK;
    k_gemm<1,2,128,128><<<dim3(HIDDENn/128, ROWS_PER_CHUNK/128), blk, 0, stream>>>(
        ln2pad, wTf1, KCONV, rbase, 0, bn1_s, bn1_sh, nullptr, hc);
    k_gemm<0,3,128,64><<<dim3(192/64, ROWS_PER_CHUNK/128), blk, 0, stream>>>(
        hc, wTf2, 768, 0, rbase, bn2_s, bn2_sh, xmid, outp);
  }
}

// Round 5
// 1144.139 us; speedup vs baseline: 1.3340x; 1.2349x over previous
//
#include <hip/hip_runtime.h>
#include <hip/hip_bf16.h>
#include <math.h>

#define DEVINL __device__ __forceinline__

typedef __bf16 bf16x8 __attribute__((ext_vector_type(8)));
typedef float  f32x4  __attribute__((ext_vector_type(4)));

DEVINL float bf2f(unsigned short h){ return __builtin_bit_cast(float, (unsigned)h << 16); }
DEVINL unsigned short f2bf(float f){
  unsigned u = __builtin_bit_cast(unsigned, f);
  u += 0x7fffu + ((u >> 16) & 1u);
  return (unsigned short)(u >> 16);
}

// direct global->LDS DMA, 16B per lane (lds dest must be wave-uniform base + lane*16)
DEVINL void gl16(const unsigned short* g, unsigned short* l){
  __builtin_amdgcn_global_load_lds((const __attribute__((address_space(1))) unsigned int*)g,
                                   (__attribute__((address_space(3))) unsigned int*)l,
                                   16, 0, 0);
}

// ---- problem constants ----
#define Bn 32
#define Hn 56
#define Wn 56
#define Cn 192
#define WSz 7
#define SHIFTn 3
#define HEADSn 6
#define HDn 32
#define NWIN 49
#define NPIX (Bn*Hn*Wn)       /* 100352 == 2048*49 */
#define HIDDENn 768
#define KCONV (9*Cn)          /* 1728 */
#define PADH 58
#define QKSCALE 0.17677669529663687f

DEVINL float wave_sum(float v){
  #pragma unroll
  for (int off=32; off; off>>=1) v += __shfl_xor(v, off, 64);
  return v;
}

// ---------------- LN1 (fp32 in) + roll(-3,-3) + window partition -> h [100352][192] bf16 ----------------
__global__ __launch_bounds__(256) void k_ln1(const float* __restrict__ x,
                                             const float* __restrict__ g,
                                             const float* __restrict__ bb,
                                             unsigned short* __restrict__ h)
{
  int row  = blockIdx.x*4 + (threadIdx.x >> 6);
  int lane = threadIdx.x & 63;
  int win = row / NWIN, n = row % NWIN;
  int b = win >> 6, rem = win & 63, wh = rem >> 3, ww = rem & 7;
  int i = n / WSz, j = n % WSz;
  int rr = (wh*WSz + i + SHIFTn) % Hn;
  int cc = (ww*WSz + j + SHIFTn) % Wn;
  const float* xr = x + (size_t)((b*Hn + rr)*Wn + cc)*Cn;
  float v0 = xr[lane], v1 = xr[lane+64], v2 = xr[lane+128];
  float s  = wave_sum(v0+v1+v2);
  float sq = wave_sum(v0*v0+v1*v1+v2*v2);
  float mu = s * (1.0f/Cn);
  float var = sq * (1.0f/Cn) - mu*mu;
  float rs = rsqrtf(var + 1e-3f);
  unsigned short* hr = h + (size_t)row*Cn;
  hr[lane]     = f2bf((v0-mu)*rs*g[lane]     + bb[lane]);
  hr[lane+64]  = f2bf((v1-mu)*rs*g[lane+64]  + bb[lane+64]);
  hr[lane+128] = f2bf((v2-mu)*rs*g[lane+128] + bb[lane+128]);
}

// ---------------- LN2 on xmid(fp32) -> zero-padded bf16 buffer [32][58][58][192] ----------------
__global__ __launch_bounds__(256) void k_ln2(const float* __restrict__ xmid,
                                             const float* __restrict__ g,
                                             const float* __restrict__ bb,
                                             unsigned short* __restrict__ out)
{
  int p    = blockIdx.x*4 + (threadIdx.x >> 6);
  int lane = threadIdx.x & 63;
  int b = p / (Hn*Wn), rc = p % (Hn*Wn);
  int r = rc / Wn, c = rc % Wn;
  const float* xr = xmid + (size_t)p*Cn;
  float v0 = xr[lane], v1 = xr[lane+64], v2 = xr[lane+128];
  float s  = wave_sum(v0+v1+v2);
  float sq = wave_sum(v0*v0+v1*v1+v2*v2);
  float mu = s * (1.0f/Cn);
  float var = sq * (1.0f/Cn) - mu*mu;
  float rs = rsqrtf(var + 1e-3f);
  unsigned short* orow = out + (size_t)((b*PADH + r + 1)*PADH + (c + 1))*Cn;
  orow[lane]     = f2bf((v0-mu)*rs*g[lane]     + bb[lane]);
  orow[lane+64]  = f2bf((v1-mu)*rs*g[lane+64]  + bb[lane+64]);
  orow[lane+128] = f2bf((v2-mu)*rs*g[lane+128] + bb[lane+128]);
}

// ---------------- transpose + fp32->bf16: out[n*K+k] = bf16(in[k*N+n]) ----------------
__global__ __launch_bounds__(256) void k_transpose(const float* __restrict__ in,
                                                   unsigned short* __restrict__ out,
                                                   int K, int N)
{
  int idx = blockIdx.x*256 + threadIdx.x;
  if (idx < K*N){ int k = idx / N, n = idx - k*N; out[(size_t)n*K + k] = f2bf(in[idx]); }
}

// ---------------- fused windowed attention: one block per (head, chunk-local window) ----------------
__global__ __launch_bounds__(256) void k_attn(const unsigned short* __restrict__ qkv, // chunk-local bf16
                                              const float* __restrict__ bias_table,   // fp32
                                              unsigned short* __restrict__ o,          // global rows bf16
                                              int win_base)
{
  __shared__ float qs[NWIN][HDn], ks[NWIN][HDn], vs[NWIN][HDn], S[NWIN][NWIN+1];
  int head = blockIdx.x, lwin = blockIdx.y;
  int gwin = win_base + lwin;
  int tid = threadIdx.x;
  const unsigned short* base = qkv + (size_t)lwin*NWIN*576 + head*HDn;
  for (int t = tid; t < NWIN*HDn; t += 256){
    int n = t >> 5, d = t & 31;
    const unsigned short* rp = base + (size_t)n*576 + d;
    qs[n][d] = bf2f(rp[0]) * QKSCALE;
    ks[n][d] = bf2f(rp[192]);
    vs[n][d] = bf2f(rp[384]);
  }
  __syncthreads();
  int rem = gwin & 63, wh = rem >> 3, ww = rem & 7;
  for (int t = tid; t < NWIN*NWIN; t += 256){
    int p = t / NWIN, q = t - p*NWIN;
    float acc = 0.f;
    #pragma unroll
    for (int d = 0; d < HDn; ++d) acc += qs[p][d]*ks[q][d];
    int pi = p/7, pj = p%7, qi = q/7, qj = q%7;
    int rel = (pi-qi+6)*13 + (pj-qj+6);
    acc += bias_table[rel*HEADSn + head];
    int pr = wh*7+pi, pc = ww*7+pj, qr = wh*7+qi, qc = ww*7+qj;
    int cp = (pr<49?0:(pr<53?1:2))*3 + (pc<49?0:(pc<53?1:2));
    int cq = (qr<49?0:(qr<53?1:2))*3 + (qc<49?0:(qc<53?1:2));
    if (cp != cq) acc -= 100.0f;
    S[p][q] = acc;
  }
  __syncthreads();
  if (tid < NWIN){
    float m = -1e30f;
    for (int q=0;q<NWIN;++q) m = fmaxf(m, S[tid][q]);
    float sum = 0.f;
    for (int q=0;q<NWIN;++q){ float e = expf(S[tid][q]-m); S[tid][q]=e; sum+=e; }
    float inv = 1.0f/sum;
    for (int q=0;q<NWIN;++q) S[tid][q] *= inv;
  }
  __syncthreads();
  for (int t = tid; t < NWIN*HDn; t += 256){
    int n = t >> 5, d = t & 31;
    float acc = 0.f;
    for (int m=0;m<NWIN;++m) acc += S[n][m]*vs[m][d];
    o[((size_t)gwin*NWIN + n)*Cn + head*HDn + d] = f2bf(acc);
  }
}

// ---------------- MFMA GEMM (m97 structure): C = A(bf16) * Bt(bf16)^T ----------------
// Tile BMt x BNt, BK=32, 4 waves in 2x2, each wave (BMt/32)x(BNt/32) frags of 16x16x32.
// Staging: direct global->LDS DMA, unpadded As[BMt][32]/Bs[BNt][32] (LDS byte off == tid*16).
// AMODE 0: A direct [.][K] at rows (a_rbase + local).  AMODE 1: implicit im2col from
//          padded ln2 [32][58][58][192] (tap uniform per BK: 192%32==0).
// EPI 0: +bias(e0) -> bf16 out[lrow*576+col]
// EPI 1: +bias(e0), window-reverse+roll scatter, +shortcut(e2 fp32) -> fp32 out (global rows)
// EPI 2: *e0+e1, exact GELU -> bf16 out[lrow*768+col]
// EPI 3: *e0+e1, + e2(fp32 xmid, global rows) -> fp32 out (global rows)
template<int AMODE, int EPI, int BMt, int BNt>
__global__ __launch_bounds__(256) void k_gemm(const unsigned short* __restrict__ A,
                                              const unsigned short* __restrict__ Bt,
                                              int K, int a_rbase, int o_rbase,
                                              const float* __restrict__ e0,
                                              const float* __restrict__ e1,
                                              const float* __restrict__ e2,
                                              void* __restrict__ out)
{
  constexpr int WMT = BMt/32, WNT = BNt/32;   // frags per wave
  constexpr int NIA = BMt/64, NIB = BNt/64;   // 64-row staging issues
  __shared__ __align__(16) unsigned short As[BMt*32];
  __shared__ __align__(16) unsigned short Bs[BNt*32];
  int tid = threadIdx.x;
  int bm = blockIdx.y * BMt, bn = blockIdx.x * BNt;
  int wave = tid >> 6, lane = tid & 63;
  int l15 = lane & 15, quad = lane >> 4;
  int wm = (wave & 1) * (BMt/2), wn = (wave >> 1) * (BNt/2);

  int srow = tid >> 2;          // staging row within a 64-row issue
  int kc   = (tid & 3) * 8;     // k element offset (8 bf16 = 16 B)

  size_t abase[NIA];
  #pragma unroll
  for (int i=0;i<NIA;++i){
    int lrow = bm + i*64 + srow;
    if (AMODE == 0) abase[i] = (size_t)(a_rbase + lrow) * K + kc;
    else {
      int grow = a_rbase + lrow;
      int b = grow / (Hn*Wn), rc = grow % (Hn*Wn);
      int r = rc / Wn, c = rc - r*Wn;
      abase[i] = (size_t)((b*PADH + r)*PADH + c) * Cn + kc;
    }
  }
  size_t bbase[NIB];
  #pragma unroll
  for (int i=0;i<NIB;++i) bbase[i] = (size_t)(bn + i*64 + srow) * K + kc;

  f32x4 acc[WMT][WNT] = {};

  int nkb = K / 32;
  for (int kb = 0; kb < nkb; ++kb){
    int k0 = kb * 32;
    size_t aoff;
    if (AMODE == 0) aoff = (size_t)k0;
    else {
      int tap = k0 / Cn, ci = k0 - tap*Cn;   // uniform across BK block
      int dh = tap/3, dw = tap - dh*3;
      aoff = (size_t)((dh*PADH + dw)*Cn + ci);
    }
    #pragma unroll
    for (int i=0;i<NIA;++i)
      gl16(A + abase[i] + aoff, &As[i*64*32] + (size_t)tid*8);
    #pragma unroll
    for (int i=0;i<NIB;++i)
      gl16(Bt + bbase[i] + (size_t)k0, &Bs[i*64*32] + (size_t)tid*8);
    __syncthreads();   // drains vmcnt: DMA complete

    bf16x8 af[WMT], bfr[WNT];
    #pragma unroll
    for (int mt=0;mt<WMT;++mt) af[mt]  = *(const bf16x8*)&As[(wm + mt*16 + l15)*32 + quad*8];
    #pragma unroll
    for (int nt=0;nt<WNT;++nt) bfr[nt] = *(const bf16x8*)&Bs[(wn + nt*16 + l15)*32 + quad*8];
    #pragma unroll
    for (int mt=0;mt<WMT;++mt)
      #pragma unroll
      for (int nt=0;nt<WNT;++nt)
        acc[mt][nt] = __builtin_amdgcn_mfma_f32_16x16x32_bf16(af[mt], bfr[nt], acc[mt][nt], 0,0,0);
    __syncthreads();   // all consumers done before next overwrite
  }

  #pragma unroll
  for (int mt=0; mt<WMT; ++mt)
  #pragma unroll
  for (int nt=0; nt<WNT; ++nt){
    f32x4 a4 = acc[mt][nt];
    int gcol = bn + wn + nt*16 + l15;
    #pragma unroll
    for (int r=0; r<4; ++r){
      int orow = bm + wm + mt*16 + quad*4 + r;   // chunk-local
      float v = a4[r];
      if (EPI == 0){
        v += e0[gcol];
        ((unsigned short*)out)[(size_t)orow*576 + gcol] = f2bf(v);
      } else if (EPI == 1){
        v += e0[gcol];
        int grow = o_rbase + orow;
        int win = grow / NWIN, n = grow - win*NWIN;
        int b = win >> 6, rem2 = win & 63, wh = rem2 >> 3, ww = rem2 & 7;
        int ii = n / WSz, jj = n - ii*WSz;
        int fr = (wh*WSz + ii + SHIFTn) % Hn;
        int fc = (ww*WSz + jj + SHIFTn) % Wn;
        size_t idx = (size_t)((b*Hn + fr)*Wn + fc)*Cn + gcol;
        ((float*)out)[idx] = e2[idx] + v;
      } else if (EPI == 2){
        v = v * e0[gcol] + e1[gcol];
        v = 0.5f * v * (1.0f + erff(v * 0.7071067811865476f));
        ((unsigned short*)out)[(size_t)orow*HIDDENn + gcol] = f2bf(v);
      } else {
        v = v * e0[gcol] + e1[gcol];
        int grow = o_rbase + orow;
        v += e2[(size_t)grow*Cn + gcol];
        ((float*)out)[(size_t)grow*Cn + gcol] = v;
      }
    }
  }
}

extern "C" void kernel_launch(void* const* d_in, const int* in_sizes, int n_in,
                              void* d_out, int out_size, void* d_ws, size_t ws_size,
                              hipStream_t stream)
{
  const float* x        = (const float*)d_in[0];
  const float* ln1_g    = (const float*)d_in[1];
  const float* ln1_b    = (const float*)d_in[2];
  const float* w_qkv    = (const float*)d_in[3];
  const float* b_qkv    = (const float*)d_in[4];
  const float* btab     = (const float*)d_in[5];
  const float* w_proj   = (const float*)d_in[6];
  const float* b_proj   = (const float*)d_in[7];
  const float* ln2_g    = (const float*)d_in[8];
  const float* ln2_b    = (const float*)d_in[9];
  const float* w_ffn1   = (const float*)d_in[10];
  const float* bn1_s    = (const float*)d_in[11];
  const float* bn1_sh   = (const float*)d_in[12];
  const float* w_ffn2   = (const float*)d_in[13];
  const float* bn2_s    = (const float*)d_in[14];
  const float* bn2_sh   = (const float*)d_in[15];

  // ---- runtime-adaptive layout: pick fewest chunks that fit ws_size ----
  // region A (41,337,344): h [NPIX][192]bf16 (38.5MB) then ln2pad (41.34MB)
  // region 2: max(qkv chunk, hidden chunk) = hidden chunk = NPIX*768*2/nch
  // xmid fp32 (77,070,336), then 4 transposed weights (3,244,032)
  const size_t szA   = 41337344;
  const size_t xmsz  = (size_t)NPIX*Cn*4;
  const size_t wtsz  = 221184 + 73728 + 2654208 + 294912;
  int nch = 8;
  for (int cand = 1; cand <= 8; cand <<= 1){
    size_t need = szA + ((size_t)NPIX*HIDDENn*2)/cand + xmsz + wtsz + (1u<<20);
    if (need <= ws_size){ nch = cand; break; }
  }
  const int mc = NPIX / nch;           // rows per chunk (mult of 128)
  const int wc = 2048 / nch;           // windows per chunk

  char* ws = (char*)d_ws;
  size_t off = 0;
  unsigned short* h      = (unsigned short*)(ws + off);
  unsigned short* ln2pad = (unsigned short*)(ws + off);  off += szA;
  unsigned short* qc     = (unsigned short*)(ws + off);
  unsigned short* hc     = (unsigned short*)(ws + off);  off += ((size_t)NPIX*HIDDENn*2)/nch;
  float*          xmid   = (float*)(ws + off);           off += xmsz;
  unsigned short* wTq    = (unsigned short*)(ws + off);  off += 221184;
  unsigned short* wTp    = (unsigned short*)(ws + off);  off += 73728;
  unsigned short* wTf1   = (unsigned short*)(ws + off);  off += 2654208;
  unsigned short* wTf2   = (unsigned short*)(ws + off);
  float*          outp   = (float*)d_out;
  unsigned short* obuf   = (unsigned short*)d_out;   // bf16 scratch: dead before final fp32 write

  dim3 blk(256);

  // weight transposes + bf16 cast (tiny)
  k_transpose<<<(192*576 + 255)/256,  blk, 0, stream>>>(w_qkv,  wTq,  192, 576);
  k_transpose<<<(192*192 + 255)/256,  blk, 0, stream>>>(w_proj, wTp,  192, 192);
  k_transpose<<<(1728*768 + 255)/256, blk, 0, stream>>>(w_ffn1, wTf1, 1728, 768);
  k_transpose<<<(768*192 + 255)/256,  blk, 0, stream>>>(w_ffn2, wTf2, 768, 192);

  // LN1 + roll + window partition (fp32 -> bf16)
  k_ln1<<<NPIX/4, blk, 0, stream>>>(x, ln1_g, ln1_b, h);

  // QKV GEMM + attention, nch chunks
  for (int c = 0; c < nch; ++c){
    int rbase = c * mc;
    k_gemm<0,0,128,64><<<dim3(576/64, mc/128), blk, 0, stream>>>(
        h, wTq, 192, rbase, 0, b_qkv, nullptr, nullptr, qc);
    k_attn<<<dim3(HEADSn, wc), blk, 0, stream>>>(qc, btab, obuf, c*wc);
  }

  // proj GEMM + window reverse + roll + shortcut(x fp32) -> xmid (fp32), full M
  k_gemm<0,1,128,64><<<dim3(192/64, NPIX/128), blk, 0, stream>>>(
      obuf, wTp, 192, 0, 0, b_proj, nullptr, x, xmid);

  // LN2 into zero-padded bf16 buffer
  hipMemsetAsync(ln2pad, 0, (size_t)Bn*PADH*PADH*Cn*2, stream);
  k_ln2<<<NPIX/4, blk, 0, stream>>>(xmid, ln2_g, ln2_b, ln2pad);

  // FFN: conv3x3(im2col)+bn1+GELU -> hc; conv1x1+bn2+residual -> fp32 out, nch chunks
  // conv tile: 128x128 when chunks are big enough for a healthy grid, else 128x64
  for (int c = 0; c < nch; ++c){
    int rbase = c * mc;
    if (nch <= 4)
      k_gemm<1,2,128,128><<<dim3(HIDDENn/128, mc/128), blk, 0, stream>>>(
          ln2pad, wTf1, KCONV, rbase, 0, bn1_s, bn1_sh, nullptr, hc);
    else
      k_gemm<1,2,128,64><<<dim3(HIDDENn/64, mc/128), blk, 0, stream>>>(
          ln2pad, wTf1, KCONV, rbase, 0, bn1_s, bn1_sh, nullptr, hc);
    k_gemm<0,3,128,64><<<dim3(192/64, mc/128), blk, 0, stream>>>(
        hc, wTf2, 768, 0, rbase, bn2_s, bn2_sh, xmid, outp);
  }
}